// Round 3
// baseline (401.266 us; speedup 1.0000x reference)
//
#include <hip/hip_runtime.h>
#include <math.h>

typedef _Float16 f16;
typedef _Float16 f16x4 __attribute__((ext_vector_type(4)));
typedef _Float16 f16x8 __attribute__((ext_vector_type(8)));
typedef float f32x16 __attribute__((ext_vector_type(16)));

// ---------------------------------------------------------------------------
// Repack weights (96, V, K) fp32 -> wpack[t][ch][VP] f16, zero-padded v >= V.
// ---------------------------------------------------------------------------
template<int V, int K, int VP>
__global__ void repack_kernel(const float* __restrict__ w, f16* __restrict__ wp) {
    int i = blockIdx.x * 256 + threadIdx.x;
    if (i >= K * 96 * VP) return;
    int v = i % VP, ch = (i / VP) % 96, t = i / (VP * 96);
    float val = (v < V) ? w[(ch * V + v) * K + t] : 0.f;
    wp[i] = (f16)val;
}

// ---------------------------------------------------------------------------
// Conv1d(valid)+bias+relu+maxpool as implicit GEMM, 32x32x16 f16 MFMA.
// 4 waves/block; each wave computes ALL 96 channels (3 col-tiles) for TPW
// row-tiles -> each A-fragment LDS read feeds 3 MFMAs (N-reuse, -3x LDS).
// B (weights) for all taps x ksteps x 3 cols held in 192 VGPRs.
// LDS: s_in[LP][RS] f16, pos-major; 16B slots XOR-swizzled by (row>>3)&3
// so stride-RSB reads AND staging writes are bank-conflict-free.
// 2 blocks/CU (LDS <= 80,640 B) so staging overlaps the other block's MFMA.
// ---------------------------------------------------------------------------
template<int V, int L, int KT, int VP, int KSTEPS, int LP, int RS, int LOUT, int TPW>
__global__ __launch_bounds__(256, 2) void conv_mfma_kernel(
    const float* __restrict__ in,    // (B, V, L) fp32
    const f16*   __restrict__ wp,    // (KT, 96, VP) f16
    const float* __restrict__ bias,  // (96)
    float* __restrict__ feat,        // (B, 192)
    int feat_off)
{
    constexpr int RSB    = RS * 2;     // row stride in bytes (16B-aligned)
    constexpr int DATA_B = VP * 2;     // payload bytes per row (4 or 8 slots)
    constexpr int NQ     = V / 4;      // full vocab quads
    static_assert(VP == KSTEPS * 16, "K tiling");
    static_assert(RSB % 16 == 0 && DATA_B <= RSB, "row alignment");
    __shared__ __align__(16) char s_raw[LP * RSB];

    const int tid  = threadIdx.x;
    const int b    = blockIdx.x;
    const int wave = tid >> 6;
    const int lane = tid & 63;
    const int q    = lane >> 5;        // k-half
    const int r    = lane & 31;        // row/col within 32-tile

    // ---- B preload: KT x KSTEPS x 3 col-tiles, per-lane contiguous 16B ----
    f16x8 bf[KT][KSTEPS][3];
    #pragma unroll
    for (int t = 0; t < KT; ++t)
        #pragma unroll
        for (int ks = 0; ks < KSTEPS; ++ks)
            #pragma unroll
            for (int c = 0; c < 3; ++c)
                bf[t][ks][c] = *(const f16x8*)(wp + ((t * 96 + c * 32 + r) * VP + ks * 16 + q * 8));

    // ---- stage input transposed fp32->f16, swizzled b64 writes ----
    const float* gin = in + (size_t)b * (V * L);
    for (int i = tid; i < NQ * L; i += 256) {
        int q4 = i / L, p = i - q4 * L;
        const float* gp = gin + q4 * 4 * L + p;
        f16x4 hv = { (f16)gp[0], (f16)gp[L], (f16)gp[2 * L], (f16)gp[3 * L] };
        int off = (8 * q4) ^ (((p >> 3) & 3) << 4);
        *(f16x4*)(s_raw + p * RSB + off) = hv;
    }
    if constexpr (NQ * 4 < V) {        // tail vocab row + zero pad (v24..31)
        for (int p = tid; p < L; p += 256) {
            f16x8 hv = {};
            hv[0] = (f16)gin[NQ * 4 * L + p];
            int off = (NQ * 8) ^ (((p >> 3) & 3) << 4);
            *(f16x8*)(s_raw + p * RSB + off) = hv;
        }
    }
    {   // zero pad rows L..LP-1 (swizzle-invariant: whole payload zero)
        constexpr int SPR = DATA_B / 16;
        for (int i = tid; i < (LP - L) * SPR; i += 256) {
            int row = L + i / SPR, s8 = i % SPR;
            f16x8 z = {};
            *(f16x8*)(s_raw + row * RSB + s8 * 16) = z;
        }
    }
    __syncthreads();

    // ---- main loop: TPW row-tiles per wave, all 96 channels ----
    float runmax[3] = { -3.0e38f, -3.0e38f, -3.0e38f };
    for (int it = 0; it < TPW; ++it) {
        const int p0 = (wave * TPW + it) * 32;
        f32x16 acc[3] = {};
        #pragma unroll
        for (int t = 0; t < KT; ++t) {
            int row = p0 + r + t;
            if (row > LP - 1) row = LP - 1;        // clamped row is zero
            const char* ap = s_raw + row * RSB;
            const int swz = ((row >> 3) & 3) << 4;
            #pragma unroll
            for (int ks = 0; ks < KSTEPS; ++ks) {
                f16x8 af = *(const f16x8*)(ap + ((ks * 32 + q * 16) ^ swz));
                #pragma unroll
                for (int c = 0; c < 3; ++c)
                    acc[c] = __builtin_amdgcn_mfma_f32_32x32x16_f16(af, bf[t][ks][c], acc[c], 0, 0, 0);
            }
        }
        if (p0 + 32 <= LOUT) {
            #pragma unroll
            for (int c = 0; c < 3; ++c)
                #pragma unroll
                for (int i = 0; i < 16; ++i) runmax[c] = fmaxf(runmax[c], acc[c][i]);
        } else {
            #pragma unroll
            for (int c = 0; c < 3; ++c)
                #pragma unroll
                for (int i = 0; i < 16; ++i) {
                    int rr = (i & 3) + 8 * (i >> 2) + 4 * q;   // C/D row map
                    if (p0 + rr < LOUT) runmax[c] = fmaxf(runmax[c], acc[c][i]);
                }
        }
    }
    #pragma unroll
    for (int c = 0; c < 3; ++c)
        runmax[c] = fmaxf(runmax[c], __shfl_xor(runmax[c], 32, 64));

    __syncthreads();                    // s_in dead; reuse as s_red[4][96]
    float* s_red = (float*)s_raw;
    if (lane < 32) {
        #pragma unroll
        for (int c = 0; c < 3; ++c) s_red[wave * 96 + c * 32 + r] = runmax[c];
    }
    __syncthreads();
    if (tid < 96) {
        float m = fmaxf(fmaxf(s_red[tid], s_red[96 + tid]),
                        fmaxf(s_red[192 + tid], s_red[288 + tid]));
        feat[(size_t)b * 192 + feat_off + tid] = fmaxf(m + bias[tid], 0.f);
    }
}

// ---------------------------------------------------------------------------
// Gram + L2 normalize + readout (4 samples/block, one wave each).
// ---------------------------------------------------------------------------
__global__ __launch_bounds__(256) void gram_affinity_kernel(
    const float* __restrict__ feat, const float* __restrict__ w_aff,
    const float* __restrict__ b_aff, float* __restrict__ out, int B)
{
    const int lane = threadIdx.x & 63;
    const int wid  = threadIdx.x >> 6;
    const int b    = blockIdx.x * 4 + wid;

    __shared__ float s_x[4][192];

    if (b < B) {
        const float* fp = feat + (size_t)b * 192;
        for (int i = lane; i < 192; i += 64) s_x[wid][i] = fp[i];
    }
    __syncthreads();

    if (b < B) {
        float ssum = 0.f, sdot = 0.f;
        #pragma unroll
        for (int t = 0; t < 16; ++t) {
            const int jk = t * 64 + lane;
            const int j = jk >> 5, k = jk & 31;
            float g = 0.f;
            #pragma unroll
            for (int i = 0; i < 6; ++i)
                g = fmaf(s_x[wid][i * 32 + j], s_x[wid][i * 32 + k], g);
            ssum = fmaf(g, g, ssum);
            sdot = fmaf(g, w_aff[jk], sdot);
        }
        #pragma unroll
        for (int off = 32; off >= 1; off >>= 1) {
            ssum += __shfl_xor(ssum, off, 64);
            sdot += __shfl_xor(sdot, off, 64);
        }
        if (lane == 0) out[b] = sdot / (sqrtf(ssum) + 1e-12f) + b_aff[0];
    }
}

extern "C" void kernel_launch(void* const* d_in, const int* in_sizes, int n_in,
                              void* d_out, int out_size, void* d_ws, size_t ws_size,
                              hipStream_t stream)
{
    const float* protein = (const float*)d_in[0];  // (B, 25, 1000)
    const float* ligand  = (const float*)d_in[1];  // (B, 64, 100)
    const float* w_pro   = (const float*)d_in[2];  // (96, 25, 8)
    const float* b_pro   = (const float*)d_in[3];  // (96,)
    const float* w_lig   = (const float*)d_in[4];  // (96, 64, 4)
    const float* b_lig   = (const float*)d_in[5];  // (96,)
    const float* w_aff   = (const float*)d_in[6];  // (1024,)
    const float* b_aff   = (const float*)d_in[7];  // (1,)
    float* out = (float*)d_out;
    const int B = out_size;                        // 4096

    float* feat   = (float*)d_ws;                              // (B,192) f32
    f16*   wpackP = (f16*)((char*)d_ws + (size_t)B * 192 * 4); // 8*96*32 f16
    f16*   wpackL = wpackP + 8 * 96 * 32;                      // 4*96*64 f16

    repack_kernel<25, 8, 32><<<96, 256, 0, stream>>>(w_pro, wpackP);
    repack_kernel<64, 4, 64><<<96, 256, 0, stream>>>(w_lig, wpackL);

    // ligand branch -> feat[:, 0:96]
    conv_mfma_kernel<64, 100, 4, 64, 4, 104, 72, 97, 1>
        <<<B, 256, 0, stream>>>(ligand, wpackL, b_lig, feat, 0);
    // protein branch -> feat[:, 96:192]
    conv_mfma_kernel<25, 1000, 8, 32, 2, 1008, 40, 993, 8>
        <<<B, 256, 0, stream>>>(protein, wpackP, b_pro, feat, 96);

    gram_affinity_kernel<<<(B + 3) / 4, 256, 0, stream>>>(feat, w_aff, b_aff, out, B);
}